// Round 15
// baseline (2256.689 us; speedup 1.0000x reference)
//
#include <hip/hip_runtime.h>
#include <hip/hip_cooperative_groups.h>
#include <math.h>

namespace cg = cooperative_groups;

#define B 8
#define LATD 512
#define PT 45376
#define FIN 192
#define FH 64
#define OW1 0
#define OB1 12288
#define OW2 12352
#define OB2 20544
#define OWS 20672
#define OBS 45248
#define KC 16

__device__ __forceinline__ float gk_at(int ky, int kx){
  const float a = 0.60653065971263342f;
  const float inv = 1.0f / ((1.0f + 2.0f*a) * (1.0f + 2.0f*a));
  float wy = (ky==1) ? 1.0f : a;
  float wx = (kx==1) ? 1.0f : a;
  return wy * wx * inv;
}

__global__ void k_hyper(const float* __restrict__ lat, const float* __restrict__ hw,
                        const float* __restrict__ hb, float* __restrict__ p){
  __shared__ float slat[B*LATD];
  for (int idx = threadIdx.x; idx < B*LATD; idx += 256) slat[idx] = lat[idx];
  __syncthreads();
  int j = blockIdx.x*256 + threadIdx.x;
  if (j >= PT) return;
  float acc[B];
#pragma unroll
  for (int b=0;b<B;++b) acc[b]=0.f;
  for (int k=0;k<LATD;++k){
    float w = hw[(size_t)k*PT + j];
#pragma unroll
    for (int b=0;b<B;++b) acc[b] = fmaf(slat[b*LATD+k], w, acc[b]);
  }
  float bias = hb[j];
#pragma unroll
  for (int b=0;b<B;++b) p[(size_t)b*PT + j] = acc[b] + bias;
}

__global__ void k_init(const float* __restrict__ noise, float* __restrict__ out){
  int bc = blockIdx.x;
  int t = threadIdx.x;
  int y = t >> 4, x = t & 15;
  const float* src = noise + (size_t)bc*256;
  float acc = 0.f;
#pragma unroll
  for (int ky=0;ky<3;++ky){
    int yy = y+ky-1; if (yy < 0 || yy > 15) continue;
#pragma unroll
    for (int kx=0;kx<3;++kx){
      int xx = x+kx-1; if (xx < 0 || xx > 15) continue;
      acc = fmaf(gk_at(ky,kx), src[yy*16+xx], acc);
    }
  }
  out[(size_t)bc*256 + t] = acc;
}

// load one float4 of normalized x: channels [out(64) ; sob(128)]
__device__ __forceinline__ float4 ldx(const float* __restrict__ out, const float* __restrict__ sob,
                                      const float* __restrict__ stats,
                                      int b, int i, int off, int HW){
  const float* src = (i < 64) ? out + ((size_t)(b*64+i))*(size_t)HW
                              : sob + ((size_t)(b*128+(i-64)))*(size_t)HW;
  float4 v = *(const float4*)(src + off);
  float c = stats[(b*192+i)*2], r = stats[(b*192+i)*2+1];
  v.x = fmaf(v.x, r, c); v.y = fmaf(v.y, r, c);
  v.z = fmaf(v.z, r, c); v.w = fmaf(v.w, r, c);
  return v;
}

// --- device helpers shared by coop kernel and discrete fallback bodies ---
__device__ void sobstat_body(const float* __restrict__ src, float* __restrict__ dxp,
                             float* __restrict__ dyp, float* __restrict__ stats,
                             float* rbufRaw, int statbase, int H, int lgH, int HW,
                             int tid, int nthr){
  float s0=0.f,q0=0.f,sx=0.f,qx=0.f,sy=0.f,qy=0.f;
  for (int px = tid*4; px < HW; px += nthr*4){
    int y = px >> lgH, x = px & (H-1);
    float rm[6], rc[6], rp[6];
    float4 v = *(const float4*)(src + px);
    rc[1]=v.x; rc[2]=v.y; rc[3]=v.z; rc[4]=v.w;
    rc[0] = (x>0)     ? src[px-1] : 0.f;
    rc[5] = (x+4 < H) ? src[px+4] : 0.f;
    s0 += v.x+v.y+v.z+v.w;
    q0 += v.x*v.x+v.y*v.y+v.z*v.z+v.w*v.w;
    if (y > 0){
      const float* r = src + px - H;
      float4 u = *(const float4*)r;
      rm[1]=u.x; rm[2]=u.y; rm[3]=u.z; rm[4]=u.w;
      rm[0] = (x>0)     ? r[-1] : 0.f;
      rm[5] = (x+4 < H) ? r[4]  : 0.f;
    } else { rm[0]=rm[1]=rm[2]=rm[3]=rm[4]=rm[5]=0.f; }
    if (y+1 < H){
      const float* r = src + px + H;
      float4 u = *(const float4*)r;
      rp[1]=u.x; rp[2]=u.y; rp[3]=u.z; rp[4]=u.w;
      rp[0] = (x>0)     ? r[-1] : 0.f;
      rp[5] = (x+4 < H) ? r[4]  : 0.f;
    } else { rp[0]=rp[1]=rp[2]=rp[3]=rp[4]=rp[5]=0.f; }
    float dxv[4], dyv[4];
#pragma unroll
    for (int j=0;j<4;++j){
      dxv[j] = ((rm[j+2]-rm[j]) + 2.f*(rc[j+2]-rc[j]) + (rp[j+2]-rp[j])) * 0.125f;
      dyv[j] = ((rp[j] + 2.f*rp[j+1] + rp[j+2]) - (rm[j] + 2.f*rm[j+1] + rm[j+2])) * 0.125f;
      sx += dxv[j]; qx = fmaf(dxv[j],dxv[j],qx);
      sy += dyv[j]; qy = fmaf(dyv[j],dyv[j],qy);
    }
    float4 o1; o1.x=dxv[0]; o1.y=dxv[1]; o1.z=dxv[2]; o1.w=dxv[3];
    float4 o2; o2.x=dyv[0]; o2.y=dyv[1]; o2.z=dyv[2]; o2.w=dyv[3];
    *(float4*)(dxp + px) = o1;
    *(float4*)(dyp + px) = o2;
  }
  float vals[6] = {s0,q0,sx,qx,sy,qy};
  float (*rbuf)[16] = (float(*)[16])rbufRaw;
  int lane = tid & 63, wid = tid >> 6;
#pragma unroll
  for (int i=0;i<6;++i){
    float v = vals[i];
#pragma unroll
    for (int off=32; off; off>>=1) v += __shfl_down(v, off, 64);
    if (lane==0) rbuf[i][wid] = v;
  }
  __syncthreads();
  if (tid < 3){
    int nw = nthr >> 6;
    float s = 0.f, q = 0.f;
    for (int i2=0;i2<nw;++i2){ s += rbuf[tid*2][i2]; q += rbuf[tid*2+1][i2]; }
    float inv = 1.0f/(float)HW;
    float m = s*inv;
    float var = fmaxf(q*inv - m*m, 0.f);
    float r = 1.0f/sqrtf(var + 1e-5f);
    stats[(statbase + tid*64)*2]   = -m*r;
    stats[(statbase + tid*64)*2+1] = r;
  }
  __syncthreads();   // rbuf free for reuse
}

// PPT=4 dyna tile body (TPX=64). bufA >= 4352 floats, bufB >= 4224 floats.
__device__ void dyna4_body(float* __restrict__ cur, const float* __restrict__ sob,
                           const float* __restrict__ stats, const float* __restrict__ pw,
                           float* bufA, float* bufB, int b, int px0, int HW,
                           int tx, int ty, int tid, float lf){
  float az[4][4], ag[4][4], ah[4][4];
#pragma unroll
  for (int k=0;k<4;++k)
#pragma unroll
    for (int j=0;j<4;++j){ az[k][j]=0.f; ag[k][j]=0.f; ah[k][j]=0.f; }
  const int wo0 = tid>>2, wk = tid&3, wo1 = 64 + wo0;
  float4 vx, vz0, vz1, v10;

  auto loadX = [&](int ci){ vx = ldx(cur,sob,stats,b, ci*KC + ty, px0 + tx*4, HW); };
  auto loadW1z = [&](int ci){
    vz0 = *(const float4*)(pw + OWS + wo0*FIN + ci*KC + wk*4);
    vz1 = *(const float4*)(pw + OWS + wo1*FIN + ci*KC + wk*4);
    v10 = *(const float4*)(pw + OW1 + wo0*FIN + ci*KC + wk*4);
  };
  auto loadW2 = [&](int ci){
    vz0 = *(const float4*)(pw + OW2 + wo0*FH + ci*KC + wk*4);
    vz1 = *(const float4*)(pw + OW2 + wo1*FH + ci*KC + wk*4);
  };
  auto writeX = [&](int bf){ *(float4*)(&bufA[bf*1088 + ty*68 + tx*4]) = vx; };
  auto writeWz = [&](int bf){
    float* WZ = &bufB[bf*2112];
    WZ[(wk*4+0)*132+wo0]=vz0.x; WZ[(wk*4+1)*132+wo0]=vz0.y; WZ[(wk*4+2)*132+wo0]=vz0.z; WZ[(wk*4+3)*132+wo0]=vz0.w;
    WZ[(wk*4+0)*132+wo1]=vz1.x; WZ[(wk*4+1)*132+wo1]=vz1.y; WZ[(wk*4+2)*132+wo1]=vz1.z; WZ[(wk*4+3)*132+wo1]=vz1.w;
  };
  auto writeW1 = [&](int bf){
    float* W1 = &bufA[2176 + bf*1088];
    W1[(wk*4+0)*68+wo0]=v10.x; W1[(wk*4+1)*68+wo0]=v10.y; W1[(wk*4+2)*68+wo0]=v10.z; W1[(wk*4+3)*68+wo0]=v10.w;
  };

  loadX(0); loadW1z(0);
  writeX(0); writeWz(0); writeW1(0);
  loadX(1); loadW1z(1);
  __syncthreads();
  for (int ci=0; ci<12; ++ci){
    int curb = ci & 1;
    if (ci < 11){ writeX(curb^1); writeWz(curb^1); writeW1(curb^1); }
    if (ci < 10){ loadX(ci+2); loadW1z(ci+2); }
    else if (ci == 10){ loadW2(0); }
#pragma unroll 4
    for (int kk=0; kk<KC; ++kk){
      float4 xa = *(const float4*)(&bufA[curb*1088 + kk*68 + tx*4]);
      float4 wz4 = *(const float4*)(&bufB[curb*2112 + kk*132 + ty*4]);
      float4 wg4 = *(const float4*)(&bufB[curb*2112 + kk*132 + 64 + ty*4]);
      float4 w14 = *(const float4*)(&bufA[2176 + curb*1088 + kk*68 + ty*4]);
      float xv[4]={xa.x,xa.y,xa.z,xa.w};
      float wzv[4]={wz4.x,wz4.y,wz4.z,wz4.w};
      float wgv[4]={wg4.x,wg4.y,wg4.z,wg4.w};
      float w1v[4]={w14.x,w14.y,w14.z,w14.w};
#pragma unroll
      for (int k=0;k<4;++k)
#pragma unroll
        for (int j=0;j<4;++j){
          az[k][j] = fmaf(wzv[k], xv[j], az[k][j]);
          ag[k][j] = fmaf(wgv[k], xv[j], ag[k][j]);
          ah[k][j] = fmaf(w1v[k], xv[j], ah[k][j]);
        }
    }
    __syncthreads();
  }
#pragma unroll
  for (int k=0;k<4;++k){
    float b1 = pw[OB1 + ty*4 + k];
    float4 r;
    r.x = fmaxf(ah[k][0]+b1, 0.f);
    r.y = fmaxf(ah[k][1]+b1, 0.f);
    r.z = fmaxf(ah[k][2]+b1, 0.f);
    r.w = fmaxf(ah[k][3]+b1, 0.f);
    *(float4*)(&bufA[(ty*4+k)*68 + tx*4]) = r;
  }
  writeWz(0);
  loadW2(1);
  __syncthreads();
  for (int ci=0; ci<4; ++ci){
    int curb = ci & 1;
    if (ci < 3) writeWz(curb^1);
    if (ci < 2) loadW2(ci+2);
#pragma unroll 4
    for (int kk=0; kk<KC; ++kk){
      float4 xa = *(const float4*)(&bufA[(ci*KC+kk)*68 + tx*4]);
      float4 wz4 = *(const float4*)(&bufB[curb*2112 + kk*132 + ty*4]);
      float4 wg4 = *(const float4*)(&bufB[curb*2112 + kk*132 + 64 + ty*4]);
      float xv[4]={xa.x,xa.y,xa.z,xa.w};
      float wzv[4]={wz4.x,wz4.y,wz4.z,wz4.w};
      float wgv[4]={wg4.x,wg4.y,wg4.z,wg4.w};
#pragma unroll
      for (int k=0;k<4;++k)
#pragma unroll
        for (int j=0;j<4;++j){
          az[k][j] = fmaf(wzv[k], xv[j], az[k][j]);
          ag[k][j] = fmaf(wgv[k], xv[j], ag[k][j]);
        }
    }
    __syncthreads();
  }
#pragma unroll
  for (int k=0;k<4;++k){
    int o = ty*4 + k;
    float bz = pw[OB2 + o]      + pw[OBS + o];
    float bg = pw[OB2 + o + 64] + pw[OBS + o + 64];
    float* op = cur + ((size_t)(b*64+o))*(size_t)HW + px0;
    float4 ov = *(const float4*)(op + tx*4);
    float r[4];
#pragma unroll
    for (int j=0;j<4;++j){
      float z = az[k][j] + bz;
      float g = ag[k][j] + bg;
      r[j] = lf * z / (1.f + expf(-g));
    }
    ov.x += r[0]; ov.y += r[1]; ov.z += r[2]; ov.w += r[3];
    *(float4*)(op + tx*4) = ov;
  }
}

__device__ void upsample_body(const float* __restrict__ s, float* __restrict__ d,
                              int H, int lgH, int tid, int nthr){
  int Hn = 2*H, HWn = Hn*Hn;
  for (int o4 = tid*4; o4 < HWn; o4 += nthr*4){
    int oy = o4 >> (lgH+1), ox0 = o4 & (Hn-1);
    int m = ox0 >> 1;
    int xm1 = (m-1 < 0)   ? 0   : m-1;
    int xp1 = (m+1 > H-1) ? H-1 : m+1;
    int xp2 = (m+2 > H-1) ? H-1 : m+2;
    float u[3][6];
#pragma unroll
    for (int ky=0; ky<3; ++ky){
      int yy = oy + ky - 1;
      if (yy < 0 || yy >= Hn){
#pragma unroll
        for (int j=0;j<6;++j) u[ky][j] = 0.f;
        continue;
      }
      int iy = yy >> 1, ry = yy & 1;
      int y0 = ry ? iy : iy-1;
      int y1 = ry ? iy+1 : iy;
      float wy0 = ry ? 0.75f : 0.25f;
      float wy1 = 1.f - wy0;
      y0 = y0 < 0 ? 0 : y0;
      y1 = y1 > H-1 ? H-1 : y1;
      const float* r0 = s + y0*H;
      const float* r1 = s + y1*H;
      float sv0 = wy0*r0[xm1] + wy1*r1[xm1];
      float sv1 = wy0*r0[m]   + wy1*r1[m];
      float sv2 = wy0*r0[xp1] + wy1*r1[xp1];
      float sv3 = wy0*r0[xp2] + wy1*r1[xp2];
      u[ky][0] = 0.75f*sv0 + 0.25f*sv1;
      u[ky][1] = 0.25f*sv0 + 0.75f*sv1;
      u[ky][2] = 0.75f*sv1 + 0.25f*sv2;
      u[ky][3] = 0.25f*sv1 + 0.75f*sv2;
      u[ky][4] = 0.75f*sv2 + 0.25f*sv3;
      u[ky][5] = 0.25f*sv2 + 0.75f*sv3;
      if (ox0 == 0)       u[ky][0] = 0.f;
      if (ox0 + 4 == Hn)  u[ky][5] = 0.f;
    }
    float res[4];
#pragma unroll
    for (int jo=0; jo<4; ++jo){
      float a = 0.f;
#pragma unroll
      for (int ky=0; ky<3; ++ky){
        a = fmaf(gk_at(ky,0), u[ky][jo],   a);
        a = fmaf(gk_at(ky,1), u[ky][jo+1], a);
        a = fmaf(gk_at(ky,2), u[ky][jo+2], a);
      }
      res[jo] = a;
    }
    float4 o; o.x=res[0]; o.y=res[1]; o.z=res[2]; o.w=res[3];
    *(float4*)(d + o4) = o;
  }
}

// ====== Cooperative small-H kernel: 256 blocks (fits 1-block/CU capacity
// estimate that rejected R13's 512 — the coop runtime validates against the
// 64KB queryable shared-mem limit). Each phase loops over its work items. ======
__global__ void __launch_bounds__(256, 3) k_small(float* __restrict__ outA, float* __restrict__ outB,
    const float* __restrict__ ca, float* __restrict__ sob, float* __restrict__ stats,
    const float* __restrict__ p, const float* __restrict__ lfp){
  cg::grid_group grid = cg::this_grid();
  __shared__ float bufA[4352];
  __shared__ float bufB[4224];
  int bid = (int)blockIdx.x;
  int tx = threadIdx.x, ty = threadIdx.y;
  int tid = ty*16 + tx;

  // phase 0: init 512 channels, 2 per block
#pragma unroll
  for (int it=0; it<2; ++it){
    int bc = bid + it*256;
    int y = tid >> 4, x = tid & 15;
    const float* src = ca + (size_t)bc*256;
    float acc = 0.f;
#pragma unroll
    for (int ky=0;ky<3;++ky){
      int yy = y+ky-1; if (yy < 0 || yy > 15) continue;
#pragma unroll
      for (int kx=0;kx<3;++kx){
        int xx = x+kx-1; if (xx < 0 || xx > 15) continue;
        acc = fmaf(gk_at(ky,kx), src[yy*16+xx], acc);
      }
    }
    outA[(size_t)bc*256 + tid] = acc;
  }
  grid.sync();

  float* cur = outA; float* oth = outB;
  int H = 16, lgH = 4;
  float lf = fminf(fmaxf(lfp[0], 0.001f), 1000.f);

  for (int c = 0; c < 12; ++c){
    int HW = H*H;
    // sobel+stats: 512 channels, 2 per block
#pragma unroll
    for (int it=0; it<2; ++it){
      int cid = bid + it*256;
      int b = cid & 7, ch = cid >> 3;
      sobstat_body(cur + ((size_t)(b*64+ch))*(size_t)HW,
                   sob + ((size_t)(b*128+ch))*(size_t)HW,
                   sob + ((size_t)(b*128+64+ch))*(size_t)HW,
                   stats, bufA, b*192 + ch, H, lgH, HW, tid, 256);
    }
    grid.sync();

    // dyna: nT = (HW/64)*8 tiles, strided over 256 blocks (tiles of one block
    // have disjoint px ranges -> in-place update race-free)
    int nT = (HW/64)*8;
    for (int t = bid; t < nT; t += 256){
      int b = t & 7;
      int px0 = (t >> 3) * 64;
      dyna4_body(cur, sob, stats, p + (size_t)b*PT, bufA, bufB, b, px0, HW, tx, ty, tid, lf);
      __syncthreads();
    }
    grid.sync();

    if ((c & 3) == 3){
      int HWn = 4*HW;
#pragma unroll
      for (int it=0; it<2; ++it){
        int plane = bid + it*256;
        upsample_body(cur + (size_t)plane*(size_t)HW, oth + (size_t)plane*(size_t)HWn,
                      H, lgH, tid, 256);
      }
      grid.sync();
      float* tsw = cur; cur = oth; oth = tsw;
      H *= 2; lgH += 1;
    }
  }
}

// ===== discrete fallback pieces (proven R13 path) =====
__global__ void __launch_bounds__(1024) k_sobstat(const float* __restrict__ out, float* __restrict__ sob,
                    float* __restrict__ stats, int H, int lgH, int HW){
  __shared__ float rbuf[6*16];
  int flat = blockIdx.x; int b = flat & 7, c = flat >> 3;
  sobstat_body(out + ((size_t)(b*64+c))*(size_t)HW,
               sob + ((size_t)(b*128+c))*(size_t)HW,
               sob + ((size_t)(b*128+64+c))*(size_t)HW,
               stats, rbuf, b*192 + c, H, lgH, HW, (int)threadIdx.x, (int)blockDim.x);
}

__global__ void __launch_bounds__(256, 3) k_dyna4(float* __restrict__ out, const float* __restrict__ sob,
                       const float* __restrict__ stats, const float* __restrict__ p,
                       const float* __restrict__ lfp, int HW){
  __shared__ float bufA[4352];
  __shared__ float bufB[4224];
  int flat = (int)(blockIdx.y*gridDim.x + blockIdx.x);
  int b   = flat & 7;
  int px0 = (flat >> 3) * 64;
  float lf = fminf(fmaxf(lfp[0], 0.001f), 1000.f);
  dyna4_body(out, sob, stats, p + (size_t)b*PT, bufA, bufB, b, px0, HW,
             (int)threadIdx.x, (int)threadIdx.y, (int)(threadIdx.y*16+threadIdx.x), lf);
}

__global__ void k_upsample(const float* __restrict__ src, float* __restrict__ dst, int H, int lgH){
  int bc = blockIdx.x;
  upsample_body(src + (size_t)bc*(size_t)(H*H), dst + (size_t)bc*(size_t)(4*H*H),
                H, lgH, (int)threadIdx.x, (int)blockDim.x);
}

// Fused dyna block @ H=128 (exact R10 proven config, PPT=8)
template<int PPT>
__global__ void __launch_bounds__(256, 3) k_dyna(float* __restrict__ out, const float* __restrict__ sob,
                       const float* __restrict__ stats, const float* __restrict__ p,
                       const float* __restrict__ lfp, int HW){
  constexpr int G     = PPT/4;
  constexpr int TPXT  = 16*PPT;
  constexpr int XST   = TPXT + 4;
  constexpr int XHALF = KC*XST;
  constexpr int W1OFF = 2*XHALF;
  constexpr int W1HALF= KC*68;
  constexpr int WEND  = W1OFF + 2*W1HALF;
  constexpr int HSZ   = 64*XST;
  constexpr int ASZ   = (WEND > HSZ) ? WEND : HSZ;
  __shared__ float bufA[ASZ];
  __shared__ float bufB[2*KC*132];

  int flat = (int)(blockIdx.y*gridDim.x + blockIdx.x);
  int b   = flat & 7;
  int px0 = (flat >> 3) * TPXT;
  int tx = threadIdx.x, ty = threadIdx.y;
  int tid = ty*16 + tx;
  const float* pw = p + (size_t)b*PT;

  float az[4][PPT], ag[4][PPT], ah[4][PPT];
#pragma unroll
  for (int k=0;k<4;++k)
#pragma unroll
    for (int j=0;j<PPT;++j){ az[k][j]=0.f; ag[k][j]=0.f; ah[k][j]=0.f; }

  const int wo0 = tid>>2, wk = tid&3, wo1 = 64 + wo0;
  float4 vx[G], vz0, vz1, v10;

  auto loadX = [&](int ci){
#pragma unroll
    for (int g=0; g<G; ++g){
      int idx = g*256 + tid;
      vx[g] = ldx(out,sob,stats,b, ci*KC + idx/(4*PPT), px0 + (idx&(4*PPT-1))*4, HW);
    }
  };
  auto loadW1z = [&](int ci){
    vz0 = *(const float4*)(pw + OWS + wo0*FIN + ci*KC + wk*4);
    vz1 = *(const float4*)(pw + OWS + wo1*FIN + ci*KC + wk*4);
    v10 = *(const float4*)(pw + OW1 + wo0*FIN + ci*KC + wk*4);
  };
  auto loadW2 = [&](int ci){
    vz0 = *(const float4*)(pw + OW2 + wo0*FH + ci*KC + wk*4);
    vz1 = *(const float4*)(pw + OW2 + wo1*FH + ci*KC + wk*4);
  };
  auto writeX = [&](int bf){
#pragma unroll
    for (int g=0; g<G; ++g){
      int idx = g*256 + tid;
      *(float4*)(&bufA[bf*XHALF + (idx/(4*PPT))*XST + (idx&(4*PPT-1))*4]) = vx[g];
    }
  };
  auto writeWz = [&](int bf){
    float* WZ = &bufB[bf*(KC*132)];
    WZ[(wk*4+0)*132+wo0]=vz0.x; WZ[(wk*4+1)*132+wo0]=vz0.y; WZ[(wk*4+2)*132+wo0]=vz0.z; WZ[(wk*4+3)*132+wo0]=vz0.w;
    WZ[(wk*4+0)*132+wo1]=vz1.x; WZ[(wk*4+1)*132+wo1]=vz1.y; WZ[(wk*4+2)*132+wo1]=vz1.z; WZ[(wk*4+3)*132+wo1]=vz1.w;
  };
  auto writeW1 = [&](int bf){
    float* W1 = &bufA[W1OFF + bf*W1HALF];
    W1[(wk*4+0)*68+wo0]=v10.x; W1[(wk*4+1)*68+wo0]=v10.y; W1[(wk*4+2)*68+wo0]=v10.z; W1[(wk*4+3)*68+wo0]=v10.w;
  };
  auto computeA = [&](int bf){
#pragma unroll 4
    for (int kk=0; kk<KC; ++kk){
      float xv[PPT];
#pragma unroll
      for (int g=0; g<G; ++g){
        float4 xa = *(const float4*)(&bufA[bf*XHALF + kk*XST + (tx+g*16)*4]);
        xv[g*4+0]=xa.x; xv[g*4+1]=xa.y; xv[g*4+2]=xa.z; xv[g*4+3]=xa.w;
      }
      float4 wz4 = *(const float4*)(&bufB[bf*(KC*132) + kk*132 + ty*4]);
      float4 wg4 = *(const float4*)(&bufB[bf*(KC*132) + kk*132 + 64 + ty*4]);
      float4 w14 = *(const float4*)(&bufA[W1OFF + bf*W1HALF + kk*68 + ty*4]);
      float wzv[4]={wz4.x,wz4.y,wz4.z,wz4.w};
      float wgv[4]={wg4.x,wg4.y,wg4.z,wg4.w};
      float w1v[4]={w14.x,w14.y,w14.z,w14.w};
#pragma unroll
      for (int k=0;k<4;++k)
#pragma unroll
        for (int j=0;j<PPT;++j){
          az[k][j] = fmaf(wzv[k], xv[j], az[k][j]);
          ag[k][j] = fmaf(wgv[k], xv[j], ag[k][j]);
          ah[k][j] = fmaf(w1v[k], xv[j], ah[k][j]);
        }
    }
  };

  loadX(0); loadW1z(0);
  writeX(0); writeWz(0); writeW1(0);
  loadX(1); loadW1z(1);
  __syncthreads();
  for (int ci=0; ci<12; ++ci){
    int cur = ci & 1;
    if (ci < 11){ writeX(cur^1); writeWz(cur^1); writeW1(cur^1); }
    if (ci < 10){ loadX(ci+2); loadW1z(ci+2); }
    else if (ci == 10){ loadW2(0); }
    computeA(cur);
    __syncthreads();
  }

#pragma unroll
  for (int k=0;k<4;++k){
    float b1 = pw[OB1 + ty*4 + k];
#pragma unroll
    for (int h=0; h<G; ++h){
      float4 r;
      r.x = fmaxf(ah[k][h*4+0]+b1, 0.f);
      r.y = fmaxf(ah[k][h*4+1]+b1, 0.f);
      r.z = fmaxf(ah[k][h*4+2]+b1, 0.f);
      r.w = fmaxf(ah[k][h*4+3]+b1, 0.f);
      *(float4*)(&bufA[(ty*4+k)*XST + (tx+h*16)*4]) = r;
    }
  }
  writeWz(0);
  loadW2(1);
  __syncthreads();

  for (int ci=0; ci<4; ++ci){
    int cur = ci & 1;
    if (ci < 3) writeWz(cur^1);
    if (ci < 2) loadW2(ci+2);
#pragma unroll 4
    for (int kk=0; kk<KC; ++kk){
      float xv[PPT];
#pragma unroll
      for (int g=0; g<G; ++g){
        float4 xa = *(const float4*)(&bufA[(ci*KC+kk)*XST + (tx+g*16)*4]);
        xv[g*4+0]=xa.x; xv[g*4+1]=xa.y; xv[g*4+2]=xa.z; xv[g*4+3]=xa.w;
      }
      float4 wz4 = *(const float4*)(&bufB[cur*(KC*132) + kk*132 + ty*4]);
      float4 wg4 = *(const float4*)(&bufB[cur*(KC*132) + kk*132 + 64 + ty*4]);
      float wzv[4]={wz4.x,wz4.y,wz4.z,wz4.w};
      float wgv[4]={wg4.x,wg4.y,wg4.z,wg4.w};
#pragma unroll
      for (int k=0;k<4;++k)
#pragma unroll
        for (int j=0;j<PPT;++j){
          az[k][j] = fmaf(wzv[k], xv[j], az[k][j]);
          ag[k][j] = fmaf(wgv[k], xv[j], ag[k][j]);
        }
    }
    __syncthreads();
  }

  float lf = fminf(fmaxf(lfp[0], 0.001f), 1000.f);
#pragma unroll
  for (int k=0;k<4;++k){
    int o = ty*4 + k;
    float bz = pw[OB2 + o]      + pw[OBS + o];
    float bg = pw[OB2 + o + 64] + pw[OBS + o + 64];
    float* op = out + ((size_t)(b*64+o))*(size_t)HW + px0;
#pragma unroll
    for (int h=0; h<G; ++h){
      float4 ov = *(const float4*)(op + (tx + h*16)*4);
      float r[4];
#pragma unroll
      for (int j=0;j<4;++j){
        float z = az[k][h*4+j] + bz;
        float g = ag[k][h*4+j] + bg;
        r[j] = lf * z / (1.f + expf(-g));
      }
      ov.x += r[0]; ov.y += r[1]; ov.z += r[2]; ov.w += r[3];
      *(float4*)(op + (tx + h*16)*4) = ov;
    }
  }
}

// Fused epilogue
__global__ void __launch_bounds__(256) k_final(const float* __restrict__ t,
    const float* __restrict__ r1w, const float* __restrict__ r1b,
    const float* __restrict__ r2w, const float* __restrict__ r2b,
    const float* __restrict__ ocw, const float* __restrict__ ocb,
    float* __restrict__ dout, int HW){
  __shared__ float Ts[64][132];
  __shared__ float Hs[64][132];
  __shared__ float Wb[64][68];
  int b = blockIdx.y;
  int tx = threadIdx.x, ty = threadIdx.y;
  int tid = ty*16 + tx;
  int px0 = blockIdx.x*128;

#pragma unroll
  for (int it=0; it<8; ++it){
    int idx = it*256 + tid;
    int ch = idx>>5, c4 = idx&31;
    *(float4*)(&Ts[ch][c4*4]) = *(const float4*)(t + ((size_t)(b*64+ch))*(size_t)HW + px0 + c4*4);
  }
#pragma unroll
  for (int it=0; it<4; ++it){
    int idx = it*256 + tid;
    int o = idx>>4, k4 = idx&15;
    float4 w = *(const float4*)(r1w + o*64 + k4*4);
    Wb[k4*4+0][o]=w.x; Wb[k4*4+1][o]=w.y; Wb[k4*4+2][o]=w.z; Wb[k4*4+3][o]=w.w;
  }
  __syncthreads();

  float acc[4][8];
#pragma unroll
  for (int k=0;k<4;++k)
#pragma unroll
    for (int j=0;j<8;++j) acc[k][j]=0.f;
#pragma unroll 4
  for (int kk=0; kk<64; ++kk){
    float4 xa = *(const float4*)(&Ts[kk][tx*4]);
    float4 xb = *(const float4*)(&Ts[kk][(tx+16)*4]);
    float4 w4 = *(const float4*)(&Wb[kk][ty*4]);
    float xv[8]={xa.x,xa.y,xa.z,xa.w,xb.x,xb.y,xb.z,xb.w};
    float wv[4]={w4.x,w4.y,w4.z,w4.w};
#pragma unroll
    for (int k=0;k<4;++k)
#pragma unroll
      for (int j=0;j<8;++j) acc[k][j] = fmaf(wv[k], xv[j], acc[k][j]);
  }
  __syncthreads();

#pragma unroll
  for (int k=0;k<4;++k){
    float bs = r1b[ty*4+k];
#pragma unroll
    for (int h=0; h<2; ++h){
      float4 r;
      r.x = fmaxf(acc[k][h*4+0]+bs, 0.f);
      r.y = fmaxf(acc[k][h*4+1]+bs, 0.f);
      r.z = fmaxf(acc[k][h*4+2]+bs, 0.f);
      r.w = fmaxf(acc[k][h*4+3]+bs, 0.f);
      *(float4*)(&Hs[ty*4+k][(tx+h*16)*4]) = r;
    }
  }
#pragma unroll
  for (int it=0; it<4; ++it){
    int idx = it*256 + tid;
    int o = idx>>4, k4 = idx&15;
    float4 w = *(const float4*)(r2w + o*64 + k4*4);
    Wb[k4*4+0][o]=w.x; Wb[k4*4+1][o]=w.y; Wb[k4*4+2][o]=w.z; Wb[k4*4+3][o]=w.w;
  }
  __syncthreads();

#pragma unroll
  for (int k=0;k<4;++k)
#pragma unroll
    for (int j=0;j<8;++j) acc[k][j]=0.f;
#pragma unroll 4
  for (int kk=0; kk<64; ++kk){
    float4 xa = *(const float4*)(&Hs[kk][tx*4]);
    float4 xb = *(const float4*)(&Hs[kk][(tx+16)*4]);
    float4 w4 = *(const float4*)(&Wb[kk][ty*4]);
    float xv[8]={xa.x,xa.y,xa.z,xa.w,xb.x,xb.y,xb.z,xb.w};
    float wv[4]={w4.x,w4.y,w4.z,w4.w};
#pragma unroll
    for (int k=0;k<4;++k)
#pragma unroll
      for (int j=0;j<8;++j) acc[k][j] = fmaf(wv[k], xv[j], acc[k][j]);
  }
#pragma unroll
  for (int k=0;k<4;++k){
    int o = ty*4 + k;
    float bs = r2b[o];
#pragma unroll
    for (int h=0; h<2; ++h){
      float4 tv = *(const float4*)(&Ts[o][(tx+h*16)*4]);
      tv.x += acc[k][h*4+0]+bs; tv.y += acc[k][h*4+1]+bs;
      tv.z += acc[k][h*4+2]+bs; tv.w += acc[k][h*4+3]+bs;
      *(float4*)(&Ts[o][(tx+h*16)*4]) = tv;
    }
  }
  __syncthreads();
  if (tid < 192){
    int c = tid>>6, kk = tid&63;
    Wb[kk][c] = ocw[c*64+kk];
  }
  __syncthreads();

  if (tid < 128){
    float a0=0.f, a1=0.f, a2=0.f;
#pragma unroll 4
    for (int kk=0; kk<64; ++kk){
      float x = Ts[kk][tid];
      a0 = fmaf(x, Wb[kk][0], a0);
      a1 = fmaf(x, Wb[kk][1], a1);
      a2 = fmaf(x, Wb[kk][2], a2);
    }
    size_t rawoff = (size_t)B*3*(size_t)HW;
    float y[3] = {a0+ocb[0], a1+ocb[1], a2+ocb[2]};
    int px = px0 + tid;
#pragma unroll
    for (int c=0;c<3;++c){
      size_t base = ((size_t)(b*3+c))*(size_t)HW + px;
      dout[base] = fminf(fmaxf(y[c],-1.f),1.f);
      dout[rawoff + base] = y[c];
    }
  }
}

extern "C" void kernel_launch(void* const* d_in, const int* in_sizes, int n_in,
                              void* d_out, int out_size, void* d_ws, size_t ws_size,
                              hipStream_t stream) {
  const float* lat = (const float*)d_in[0];
  const float* ca  = (const float*)d_in[1];
  const float* lfp = (const float*)d_in[3];
  const float* hw  = (const float*)d_in[4];
  const float* hb  = (const float*)d_in[5];
  const float* r1w = (const float*)d_in[6];
  const float* r1b = (const float*)d_in[7];
  const float* r2w = (const float*)d_in[8];
  const float* r2b = (const float*)d_in[9];
  const float* ocw = (const float*)d_in[10];
  const float* ocb = (const float*)d_in[11];
  float* dout = (float*)d_out;

  float* ws   = (float*)d_ws;
  float* p    = ws;                                     // B*PT
  float* outA = p    + (size_t)B*PT;                    // B*64*16384
  float* outB = outA + (size_t)B*64*16384;              // B*64*16384
  float* sob  = outB + (size_t)B*64*16384;              // B*128*16384
  float* stats= sob  + (size_t)B*128*16384;             // B*192*2

  k_hyper<<<dim3((PT+255)/256), dim3(256), 0, stream>>>(lat, hw, hb, p);

  // Cooperative small-H prefix (256 blocks); fall back to discrete R13 path if
  // the coop launch is rejected (capacity or capture restrictions).
  void* args[] = { (void*)&outA, (void*)&outB, (void*)&ca, (void*)&sob,
                   (void*)&stats, (void*)&p, (void*)&lfp };
  hipError_t cerr = hipLaunchCooperativeKernel((void*)k_small, dim3(256), dim3(16,16),
                                               args, 0, stream);
  if (cerr != hipSuccess){
    k_init<<<dim3(B*64), dim3(256), 0, stream>>>(ca, outA);
    float* cur = outA; float* oth = outB;
    int H = 16, lgH = 4;
    for (int c = 0; c < 12; ++c){
      int HW = H*H;
      k_sobstat<<<dim3(B*64), dim3(256), 0, stream>>>(cur, sob, stats, H, lgH, HW);
      k_dyna4<<<dim3(HW/64, B), dim3(16,16), 0, stream>>>(cur, sob, stats, p, lfp, HW);
      if ((c & 3) == 3){
        k_upsample<<<dim3(B*64), dim3(256), 0, stream>>>(cur, oth, H, lgH);
        float* tmp = cur; cur = oth; oth = tmp;
        H *= 2; lgH += 1;
      }
    }
  }

  // H=128 iterations c=12..15 (both paths leave the field in outB).
  float* cur = outB;
  int H = 128, lgH = 7, HW = 16384;
  for (int c = 12; c < 16; ++c){
    k_sobstat<<<dim3(B*64), dim3(1024), 0, stream>>>(cur, sob, stats, H, lgH, HW);
    k_dyna<8><<<dim3(HW/128, B), dim3(16,16), 0, stream>>>(cur, sob, stats, p, lfp, HW);
  }
  k_final<<<dim3(HW/128, B), dim3(16,16), 0, stream>>>(cur, r1w, r1b, r2w, r2b, ocw, ocb, dout, HW);
}

// Round 16
// 1307.147 us; speedup vs baseline: 1.7264x; 1.7264x over previous
//
#include <hip/hip_runtime.h>
#include <math.h>

#define B 8
#define LATD 512
#define PT 45376
#define FIN 192
#define FH 64
#define OW1 0
#define OB1 12288
#define OW2 12352
#define OB2 20544
#define OWS 20672
#define OBS 45248
#define KC 16     // K chunk

__device__ __forceinline__ float gk_at(int ky, int kx){
  const float a = 0.60653065971263342f;
  const float inv = 1.0f / ((1.0f + 2.0f*a) * (1.0f + 2.0f*a));
  float wy = (ky==1) ? 1.0f : a;
  float wx = (kx==1) ? 1.0f : a;
  return wy * wx * inv;
}

// p[b][j] = sum_k lat[b][k] * hyper_w[k][j] + hyper_b[j]
__global__ void k_hyper(const float* __restrict__ lat, const float* __restrict__ hw,
                        const float* __restrict__ hb, float* __restrict__ p){
  __shared__ float slat[B*LATD];
  for (int idx = threadIdx.x; idx < B*LATD; idx += 256) slat[idx] = lat[idx];
  __syncthreads();
  int j = blockIdx.x*256 + threadIdx.x;
  if (j >= PT) return;
  float acc[B];
#pragma unroll
  for (int b=0;b<B;++b) acc[b]=0.f;
  for (int k=0;k<LATD;++k){
    float w = hw[(size_t)k*PT + j];
#pragma unroll
    for (int b=0;b<B;++b) acc[b] = fmaf(slat[b*LATD+k], w, acc[b]);
  }
  float bias = hb[j];
#pragma unroll
  for (int b=0;b<B;++b) p[(size_t)b*PT + j] = acc[b] + bias;
}

// out = gauss_blur(ca_noise) at 16x16  (inst_norm(broadcast(seed)) == 0 exactly)
__global__ void k_init(const float* __restrict__ noise, float* __restrict__ out){
  int bc = blockIdx.x;
  int t = threadIdx.x;
  int y = t >> 4, x = t & 15;
  const float* src = noise + (size_t)bc*256;
  float acc = 0.f;
#pragma unroll
  for (int ky=0;ky<3;++ky){
    int yy = y+ky-1; if (yy < 0 || yy > 15) continue;
#pragma unroll
    for (int kx=0;kx<3;++kx){
      int xx = x+kx-1; if (xx < 0 || xx > 15) continue;
      acc = fmaf(gk_at(ky,kx), src[yy*16+xx], acc);
    }
  }
  out[(size_t)bc*256 + t] = acc;
}

// Fused sobel + stats: one block per (b, c<64). Reads channel once, writes dx,dy,
// and stats (c=-m*r, r). 1024 threads/block for H>=64 (TLP), 256 for small H.
__global__ void __launch_bounds__(1024) k_sobstat(const float* __restrict__ out, float* __restrict__ sob,
                    float* __restrict__ stats, int H, int lgH, int HW){
  int flat = blockIdx.x; int b = flat & 7, c = flat >> 3;
  int t = threadIdx.x;
  int stride = blockDim.x * 4;
  const float* src = out + ((size_t)(b*64+c))*(size_t)HW;
  float* dxp = sob + ((size_t)(b*128 + c))*(size_t)HW;
  float* dyp = sob + ((size_t)(b*128 + 64 + c))*(size_t)HW;
  float s0=0.f,q0=0.f,sx=0.f,qx=0.f,sy=0.f,qy=0.f;
  for (int px = t*4; px < HW; px += stride){
    int y = px >> lgH, x = px & (H-1);
    float rm[6], rc[6], rp[6];
    float4 v = *(const float4*)(src + px);
    rc[1]=v.x; rc[2]=v.y; rc[3]=v.z; rc[4]=v.w;
    rc[0] = (x>0)     ? src[px-1] : 0.f;
    rc[5] = (x+4 < H) ? src[px+4] : 0.f;
    s0 += v.x+v.y+v.z+v.w;
    q0 += v.x*v.x+v.y*v.y+v.z*v.z+v.w*v.w;
    if (y > 0){
      const float* r = src + px - H;
      float4 u = *(const float4*)r;
      rm[1]=u.x; rm[2]=u.y; rm[3]=u.z; rm[4]=u.w;
      rm[0] = (x>0)     ? r[-1] : 0.f;
      rm[5] = (x+4 < H) ? r[4]  : 0.f;
    } else { rm[0]=rm[1]=rm[2]=rm[3]=rm[4]=rm[5]=0.f; }
    if (y+1 < H){
      const float* r = src + px + H;
      float4 u = *(const float4*)r;
      rp[1]=u.x; rp[2]=u.y; rp[3]=u.z; rp[4]=u.w;
      rp[0] = (x>0)     ? r[-1] : 0.f;
      rp[5] = (x+4 < H) ? r[4]  : 0.f;
    } else { rp[0]=rp[1]=rp[2]=rp[3]=rp[4]=rp[5]=0.f; }
    float dxv[4], dyv[4];
#pragma unroll
    for (int j=0;j<4;++j){
      dxv[j] = ((rm[j+2]-rm[j]) + 2.f*(rc[j+2]-rc[j]) + (rp[j+2]-rp[j])) * 0.125f;
      dyv[j] = ((rp[j] + 2.f*rp[j+1] + rp[j+2]) - (rm[j] + 2.f*rm[j+1] + rm[j+2])) * 0.125f;
      sx += dxv[j]; qx = fmaf(dxv[j],dxv[j],qx);
      sy += dyv[j]; qy = fmaf(dyv[j],dyv[j],qy);
    }
    float4 o1; o1.x=dxv[0]; o1.y=dxv[1]; o1.z=dxv[2]; o1.w=dxv[3];
    float4 o2; o2.x=dyv[0]; o2.y=dyv[1]; o2.z=dyv[2]; o2.w=dyv[3];
    *(float4*)(dxp + px) = o1;
    *(float4*)(dyp + px) = o2;
  }
  // reduce 3 stat pairs (up to 16 waves)
  float vals[6] = {s0,q0,sx,qx,sy,qy};
  __shared__ float rbuf[6][16];
  int lane = t & 63, wid = t >> 6;
#pragma unroll
  for (int i=0;i<6;++i){
    float v = vals[i];
#pragma unroll
    for (int off=32; off; off>>=1) v += __shfl_down(v, off, 64);
    if (lane==0) rbuf[i][wid] = v;
  }
  __syncthreads();
  if (t < 3){
    int nw = blockDim.x >> 6;
    float s = 0.f, q = 0.f;
    for (int i2=0;i2<nw;++i2){ s += rbuf[t*2][i2]; q += rbuf[t*2+1][i2]; }
    float inv = 1.0f/(float)HW;
    float m = s*inv;
    float var = fmaxf(q*inv - m*m, 0.f);
    float r = 1.0f/sqrtf(var + 1e-5f);
    int ch = b*192 + c + t*64;
    stats[ch*2]   = -m*r;
    stats[ch*2+1] = r;
  }
}

// load one float4 of normalized x: channels [out(64) ; sob(128)]
__device__ __forceinline__ float4 ldx(const float* __restrict__ out, const float* __restrict__ sob,
                                      const float* __restrict__ stats,
                                      int b, int i, int off, int HW){
  const float* src = (i < 64) ? out + ((size_t)(b*64+i))*(size_t)HW
                              : sob + ((size_t)(b*128+(i-64)))*(size_t)HW;
  float4 v = *(const float4*)(src + off);
  float c = stats[(b*192+i)*2], r = stats[(b*192+i)*2+1];
  v.x = fmaf(v.x, r, c); v.y = fmaf(v.y, r, c);
  v.z = fmaf(v.z, r, c); v.w = fmaf(v.w, r, c);
  return v;
}

// Fused dyna block (R10 proven config: PPT=8 H=128 / PPT=4 small H, KC=16,
// LDS dbuf 1 barrier/chunk, padded strides, XCD batch-affinity).
// Session lore: hint 3 -> 84 VGPR, no spill for the 96-float accumulator;
// all structural variants (pad-0, PPT=16, KC=8, wave-uniform W, coop fusion)
// regressed — this is the measured family optimum (154us @128^2, VALU ~71%).
template<int PPT>
__global__ void __launch_bounds__(256, 3) k_dyna(float* __restrict__ out, const float* __restrict__ sob,
                       const float* __restrict__ stats, const float* __restrict__ p,
                       const float* __restrict__ lfp, int HW){
  constexpr int G     = PPT/4;
  constexpr int TPXT  = 16*PPT;
  constexpr int XST   = TPXT + 4;
  constexpr int XHALF = KC*XST;
  constexpr int W1OFF = 2*XHALF;
  constexpr int W1HALF= KC*68;
  constexpr int WEND  = W1OFF + 2*W1HALF;
  constexpr int HSZ   = 64*XST;
  constexpr int ASZ   = (WEND > HSZ) ? WEND : HSZ;
  __shared__ float bufA[ASZ];
  __shared__ float bufB[2*KC*132];

  int flat = (int)(blockIdx.y*gridDim.x + blockIdx.x);
  int b   = flat & 7;
  int px0 = (flat >> 3) * TPXT;
  int tx = threadIdx.x, ty = threadIdx.y;
  int tid = ty*16 + tx;
  const float* pw = p + (size_t)b*PT;

  float az[4][PPT], ag[4][PPT], ah[4][PPT];
#pragma unroll
  for (int k=0;k<4;++k)
#pragma unroll
    for (int j=0;j<PPT;++j){ az[k][j]=0.f; ag[k][j]=0.f; ah[k][j]=0.f; }

  const int wo0 = tid>>2, wk = tid&3, wo1 = 64 + wo0;
  float4 vx[G], vz0, vz1, v10;

  auto loadX = [&](int ci){
#pragma unroll
    for (int g=0; g<G; ++g){
      int idx = g*256 + tid;
      vx[g] = ldx(out,sob,stats,b, ci*KC + idx/(4*PPT), px0 + (idx&(4*PPT-1))*4, HW);
    }
  };
  auto loadW1z = [&](int ci){
    vz0 = *(const float4*)(pw + OWS + wo0*FIN + ci*KC + wk*4);
    vz1 = *(const float4*)(pw + OWS + wo1*FIN + ci*KC + wk*4);
    v10 = *(const float4*)(pw + OW1 + wo0*FIN + ci*KC + wk*4);
  };
  auto loadW2 = [&](int ci){
    vz0 = *(const float4*)(pw + OW2 + wo0*FH + ci*KC + wk*4);
    vz1 = *(const float4*)(pw + OW2 + wo1*FH + ci*KC + wk*4);
  };
  auto writeX = [&](int bf){
#pragma unroll
    for (int g=0; g<G; ++g){
      int idx = g*256 + tid;
      *(float4*)(&bufA[bf*XHALF + (idx/(4*PPT))*XST + (idx&(4*PPT-1))*4]) = vx[g];
    }
  };
  auto writeWz = [&](int bf){
    float* WZ = &bufB[bf*(KC*132)];
    WZ[(wk*4+0)*132+wo0]=vz0.x; WZ[(wk*4+1)*132+wo0]=vz0.y; WZ[(wk*4+2)*132+wo0]=vz0.z; WZ[(wk*4+3)*132+wo0]=vz0.w;
    WZ[(wk*4+0)*132+wo1]=vz1.x; WZ[(wk*4+1)*132+wo1]=vz1.y; WZ[(wk*4+2)*132+wo1]=vz1.z; WZ[(wk*4+3)*132+wo1]=vz1.w;
  };
  auto writeW1 = [&](int bf){
    float* W1 = &bufA[W1OFF + bf*W1HALF];
    W1[(wk*4+0)*68+wo0]=v10.x; W1[(wk*4+1)*68+wo0]=v10.y; W1[(wk*4+2)*68+wo0]=v10.z; W1[(wk*4+3)*68+wo0]=v10.w;
  };
  auto computeA = [&](int bf){
#pragma unroll 4
    for (int kk=0; kk<KC; ++kk){
      float xv[PPT];
#pragma unroll
      for (int g=0; g<G; ++g){
        float4 xa = *(const float4*)(&bufA[bf*XHALF + kk*XST + (tx+g*16)*4]);
        xv[g*4+0]=xa.x; xv[g*4+1]=xa.y; xv[g*4+2]=xa.z; xv[g*4+3]=xa.w;
      }
      float4 wz4 = *(const float4*)(&bufB[bf*(KC*132) + kk*132 + ty*4]);
      float4 wg4 = *(const float4*)(&bufB[bf*(KC*132) + kk*132 + 64 + ty*4]);
      float4 w14 = *(const float4*)(&bufA[W1OFF + bf*W1HALF + kk*68 + ty*4]);
      float wzv[4]={wz4.x,wz4.y,wz4.z,wz4.w};
      float wgv[4]={wg4.x,wg4.y,wg4.z,wg4.w};
      float w1v[4]={w14.x,w14.y,w14.z,w14.w};
#pragma unroll
      for (int k=0;k<4;++k)
#pragma unroll
        for (int j=0;j<PPT;++j){
          az[k][j] = fmaf(wzv[k], xv[j], az[k][j]);
          ag[k][j] = fmaf(wgv[k], xv[j], ag[k][j]);
          ah[k][j] = fmaf(w1v[k], xv[j], ah[k][j]);
        }
    }
  };

  // ---- phase A: K=0..191, 12 chunks, LDS double-buffered, 1 barrier/chunk ----
  loadX(0); loadW1z(0);
  writeX(0); writeWz(0); writeW1(0);
  loadX(1); loadW1z(1);
  __syncthreads();
  for (int ci=0; ci<12; ++ci){
    int cur = ci & 1;
    if (ci < 11){ writeX(cur^1); writeWz(cur^1); writeW1(cur^1); }
    if (ci < 10){ loadX(ci+2); loadW1z(ci+2); }
    else if (ci == 10){ loadW2(0); }
    computeA(cur);
    __syncthreads();
  }

  // ---- transition: h -> Hs (aliases X/W1 region), W2 c0 -> WZ0 ----
#pragma unroll
  for (int k=0;k<4;++k){
    float b1 = pw[OB1 + ty*4 + k];
#pragma unroll
    for (int h=0; h<G; ++h){
      float4 r;
      r.x = fmaxf(ah[k][h*4+0]+b1, 0.f);
      r.y = fmaxf(ah[k][h*4+1]+b1, 0.f);
      r.z = fmaxf(ah[k][h*4+2]+b1, 0.f);
      r.w = fmaxf(ah[k][h*4+3]+b1, 0.f);
      *(float4*)(&bufA[(ty*4+k)*XST + (tx+h*16)*4]) = r;
    }
  }
  writeWz(0);
  loadW2(1);
  __syncthreads();

  // ---- phase C: K=192..255 (h from LDS), 4 chunks, dbuf ----
  for (int ci=0; ci<4; ++ci){
    int cur = ci & 1;
    if (ci < 3) writeWz(cur^1);
    if (ci < 2) loadW2(ci+2);
#pragma unroll 4
    for (int kk=0; kk<KC; ++kk){
      float xv[PPT];
#pragma unroll
      for (int g=0; g<G; ++g){
        float4 xa = *(const float4*)(&bufA[(ci*KC+kk)*XST + (tx+g*16)*4]);
        xv[g*4+0]=xa.x; xv[g*4+1]=xa.y; xv[g*4+2]=xa.z; xv[g*4+3]=xa.w;
      }
      float4 wz4 = *(const float4*)(&bufB[cur*(KC*132) + kk*132 + ty*4]);
      float4 wg4 = *(const float4*)(&bufB[cur*(KC*132) + kk*132 + 64 + ty*4]);
      float wzv[4]={wz4.x,wz4.y,wz4.z,wz4.w};
      float wgv[4]={wg4.x,wg4.y,wg4.z,wg4.w};
#pragma unroll
      for (int k=0;k<4;++k)
#pragma unroll
        for (int j=0;j<PPT;++j){
          az[k][j] = fmaf(wzv[k], xv[j], az[k][j]);
          ag[k][j] = fmaf(wgv[k], xv[j], ag[k][j]);
        }
    }
    __syncthreads();
  }

  // ---- epilogue: out += lf * z * sigmoid(g) ----
  float lf = fminf(fmaxf(lfp[0], 0.001f), 1000.f);
#pragma unroll
  for (int k=0;k<4;++k){
    int o = ty*4 + k;
    float bz = pw[OB2 + o]      + pw[OBS + o];
    float bg = pw[OB2 + o + 64] + pw[OBS + o + 64];
    float* op = out + ((size_t)(b*64+o))*(size_t)HW + px0;
#pragma unroll
    for (int h=0; h<G; ++h){
      float4 ov = *(const float4*)(op + (tx + h*16)*4);
      float r[4];
#pragma unroll
      for (int j=0;j<4;++j){
        float z = az[k][h*4+j] + bz;
        float g = ag[k][h*4+j] + bg;
        r[j] = lf * z / (1.f + expf(-g));
      }
      ov.x += r[0]; ov.y += r[1]; ov.z += r[2]; ov.w += r[3];
      *(float4*)(op + (tx + h*16)*4) = ov;
    }
  }
}

// dst(2H x 2H) = gauss_blur( bilinear_up2(src) ), zero-padded blur, clamped bilinear.
__global__ void k_upsample(const float* __restrict__ src, float* __restrict__ dst, int H, int lgH){
  int Hn = 2*H;
  int HWn = Hn*Hn;
  int bc = blockIdx.y;
  int o4 = (blockIdx.x*256 + threadIdx.x)*4;
  const float* s = src + (size_t)bc*(size_t)(H*H);
  int oy = o4 >> (lgH+1), ox0 = o4 & (Hn-1);
  int m = ox0 >> 1;
  int xm1 = (m-1 < 0)   ? 0   : m-1;
  int xp1 = (m+1 > H-1) ? H-1 : m+1;
  int xp2 = (m+2 > H-1) ? H-1 : m+2;
  float u[3][6];
#pragma unroll
  for (int ky=0; ky<3; ++ky){
    int yy = oy + ky - 1;
    if (yy < 0 || yy >= Hn){
#pragma unroll
      for (int j=0;j<6;++j) u[ky][j] = 0.f;
      continue;
    }
    int iy = yy >> 1, ry = yy & 1;
    int y0 = ry ? iy : iy-1;
    int y1 = ry ? iy+1 : iy;
    float wy0 = ry ? 0.75f : 0.25f;
    float wy1 = 1.f - wy0;
    y0 = y0 < 0 ? 0 : y0;
    y1 = y1 > H-1 ? H-1 : y1;
    const float* r0 = s + y0*H;
    const float* r1 = s + y1*H;
    float sv0 = wy0*r0[xm1] + wy1*r1[xm1];
    float sv1 = wy0*r0[m]   + wy1*r1[m];
    float sv2 = wy0*r0[xp1] + wy1*r1[xp1];
    float sv3 = wy0*r0[xp2] + wy1*r1[xp2];
    u[ky][0] = 0.75f*sv0 + 0.25f*sv1;
    u[ky][1] = 0.25f*sv0 + 0.75f*sv1;
    u[ky][2] = 0.75f*sv1 + 0.25f*sv2;
    u[ky][3] = 0.25f*sv1 + 0.75f*sv2;
    u[ky][4] = 0.75f*sv2 + 0.25f*sv3;
    u[ky][5] = 0.25f*sv2 + 0.75f*sv3;
    if (ox0 == 0)       u[ky][0] = 0.f;
    if (ox0 + 4 == Hn)  u[ky][5] = 0.f;
  }
  float res[4];
#pragma unroll
  for (int jo=0; jo<4; ++jo){
    float a = 0.f;
#pragma unroll
    for (int ky=0; ky<3; ++ky){
      a = fmaf(gk_at(ky,0), u[ky][jo],   a);
      a = fmaf(gk_at(ky,1), u[ky][jo+1], a);
      a = fmaf(gk_at(ky,2), u[ky][jo+2], a);
    }
    res[jo] = a;
  }
  float4 o; o.x=res[0]; o.y=res[1]; o.z=res[2]; o.w=res[3];
  *(float4*)(dst + (size_t)bc*(size_t)HWn + o4) = o;
}

// Fused epilogue: h'=relu(r1w@t+r1b); t2 = t + r2w@h'+r2b; y = ocw@t2+ocb; write clip(y),raw(y)
__global__ void __launch_bounds__(256) k_final(const float* __restrict__ t,
    const float* __restrict__ r1w, const float* __restrict__ r1b,
    const float* __restrict__ r2w, const float* __restrict__ r2b,
    const float* __restrict__ ocw, const float* __restrict__ ocb,
    float* __restrict__ dout, int HW){
  __shared__ float Ts[64][132];
  __shared__ float Hs[64][132];
  __shared__ float Wb[64][68];
  int b = blockIdx.y;
  int tx = threadIdx.x, ty = threadIdx.y;
  int tid = ty*16 + tx;
  int px0 = blockIdx.x*128;

#pragma unroll
  for (int it=0; it<8; ++it){
    int idx = it*256 + tid;
    int ch = idx>>5, c4 = idx&31;
    *(float4*)(&Ts[ch][c4*4]) = *(const float4*)(t + ((size_t)(b*64+ch))*(size_t)HW + px0 + c4*4);
  }
#pragma unroll
  for (int it=0; it<4; ++it){
    int idx = it*256 + tid;
    int o = idx>>4, k4 = idx&15;
    float4 w = *(const float4*)(r1w + o*64 + k4*4);
    Wb[k4*4+0][o]=w.x; Wb[k4*4+1][o]=w.y; Wb[k4*4+2][o]=w.z; Wb[k4*4+3][o]=w.w;
  }
  __syncthreads();

  float acc[4][8];
#pragma unroll
  for (int k=0;k<4;++k)
#pragma unroll
    for (int j=0;j<8;++j) acc[k][j]=0.f;
#pragma unroll 4
  for (int kk=0; kk<64; ++kk){
    float4 xa = *(const float4*)(&Ts[kk][tx*4]);
    float4 xb = *(const float4*)(&Ts[kk][(tx+16)*4]);
    float4 w4 = *(const float4*)(&Wb[kk][ty*4]);
    float xv[8]={xa.x,xa.y,xa.z,xa.w,xb.x,xb.y,xb.z,xb.w};
    float wv[4]={w4.x,w4.y,w4.z,w4.w};
#pragma unroll
    for (int k=0;k<4;++k)
#pragma unroll
      for (int j=0;j<8;++j) acc[k][j] = fmaf(wv[k], xv[j], acc[k][j]);
  }
  __syncthreads();

#pragma unroll
  for (int k=0;k<4;++k){
    float bs = r1b[ty*4+k];
#pragma unroll
    for (int h=0; h<2; ++h){
      float4 r;
      r.x = fmaxf(acc[k][h*4+0]+bs, 0.f);
      r.y = fmaxf(acc[k][h*4+1]+bs, 0.f);
      r.z = fmaxf(acc[k][h*4+2]+bs, 0.f);
      r.w = fmaxf(acc[k][h*4+3]+bs, 0.f);
      *(float4*)(&Hs[ty*4+k][(tx+h*16)*4]) = r;
    }
  }
#pragma unroll
  for (int it=0; it<4; ++it){
    int idx = it*256 + tid;
    int o = idx>>4, k4 = idx&15;
    float4 w = *(const float4*)(r2w + o*64 + k4*4);
    Wb[k4*4+0][o]=w.x; Wb[k4*4+1][o]=w.y; Wb[k4*4+2][o]=w.z; Wb[k4*4+3][o]=w.w;
  }
  __syncthreads();

#pragma unroll
  for (int k=0;k<4;++k)
#pragma unroll
    for (int j=0;j<8;++j) acc[k][j]=0.f;
#pragma unroll 4
  for (int kk=0; kk<64; ++kk){
    float4 xa = *(const float4*)(&Hs[kk][tx*4]);
    float4 xb = *(const float4*)(&Hs[kk][(tx+16)*4]);
    float4 w4 = *(const float4*)(&Wb[kk][ty*4]);
    float xv[8]={xa.x,xa.y,xa.z,xa.w,xb.x,xb.y,xb.z,xb.w};
    float wv[4]={w4.x,w4.y,w4.z,w4.w};
#pragma unroll
    for (int k=0;k<4;++k)
#pragma unroll
      for (int j=0;j<8;++j) acc[k][j] = fmaf(wv[k], xv[j], acc[k][j]);
  }
#pragma unroll
  for (int k=0;k<4;++k){
    int o = ty*4 + k;
    float bs = r2b[o];
#pragma unroll
    for (int h=0; h<2; ++h){
      float4 tv = *(const float4*)(&Ts[o][(tx+h*16)*4]);
      tv.x += acc[k][h*4+0]+bs; tv.y += acc[k][h*4+1]+bs;
      tv.z += acc[k][h*4+2]+bs; tv.w += acc[k][h*4+3]+bs;
      *(float4*)(&Ts[o][(tx+h*16)*4]) = tv;
    }
  }
  __syncthreads();
  if (tid < 192){
    int c = tid>>6, kk = tid&63;
    Wb[kk][c] = ocw[c*64+kk];
  }
  __syncthreads();

  if (tid < 128){
    float a0=0.f, a1=0.f, a2=0.f;
#pragma unroll 4
    for (int kk=0; kk<64; ++kk){
      float x = Ts[kk][tid];
      a0 = fmaf(x, Wb[kk][0], a0);
      a1 = fmaf(x, Wb[kk][1], a1);
      a2 = fmaf(x, Wb[kk][2], a2);
    }
    size_t rawoff = (size_t)B*3*(size_t)HW;
    float y[3] = {a0+ocb[0], a1+ocb[1], a2+ocb[2]};
    int px = px0 + tid;
#pragma unroll
    for (int c=0;c<3;++c){
      size_t base = ((size_t)(b*3+c))*(size_t)HW + px;
      dout[base] = fminf(fmaxf(y[c],-1.f),1.f);
      dout[rawoff + base] = y[c];
    }
  }
}

extern "C" void kernel_launch(void* const* d_in, const int* in_sizes, int n_in,
                              void* d_out, int out_size, void* d_ws, size_t ws_size,
                              hipStream_t stream) {
  const float* lat = (const float*)d_in[0];
  const float* ca  = (const float*)d_in[1];
  const float* lfp = (const float*)d_in[3];
  const float* hw  = (const float*)d_in[4];
  const float* hb  = (const float*)d_in[5];
  const float* r1w = (const float*)d_in[6];
  const float* r1b = (const float*)d_in[7];
  const float* r2w = (const float*)d_in[8];
  const float* r2b = (const float*)d_in[9];
  const float* ocw = (const float*)d_in[10];
  const float* ocb = (const float*)d_in[11];
  float* dout = (float*)d_out;

  float* ws   = (float*)d_ws;
  float* p    = ws;                                     // B*PT
  float* outA = p    + (size_t)B*PT;                    // B*64*16384
  float* outB = outA + (size_t)B*64*16384;              // B*64*16384
  float* sob  = outB + (size_t)B*64*16384;              // B*128*16384
  float* stats= sob  + (size_t)B*128*16384;             // B*192*2

  k_hyper<<<dim3((PT+255)/256), dim3(256), 0, stream>>>(lat, hw, hb, p);
  k_init<<<dim3(B*64), dim3(256), 0, stream>>>(ca, outA);

  float* cur = outA;
  float* oth = outB;
  int H = 16, lgH = 4;
  for (int c = 0; c < 16; ++c){
    int HW = H*H;
    int sthreads = (HW >= 4096) ? 1024 : 256;
    k_sobstat<<<dim3(B*64), dim3(sthreads), 0, stream>>>(cur, sob, stats, H, lgH, HW);
    if (H >= 128)
      k_dyna<8><<<dim3(HW/128, B), dim3(16,16), 0, stream>>>(cur, sob, stats, p, lfp, HW);
    else
      k_dyna<4><<<dim3(HW/64, B), dim3(16,16), 0, stream>>>(cur, sob, stats, p, lfp, HW);
    if (c < 15 && (c & 3) == 3){
      k_upsample<<<dim3((HW*4)/1024, B*64), dim3(256), 0, stream>>>(cur, oth, H, lgH);
      float* tmp = cur; cur = oth; oth = tmp;
      H *= 2; lgH += 1;
    }
  }
  int HW = H*H;  // 16384
  k_final<<<dim3(HW/128, B), dim3(16,16), 0, stream>>>(cur, r1w, r1b, r2w, r2b, ocw, ocb, dout, HW);
}